// Round 25
// baseline (143.940 us; speedup 1.0000x reference)
//
#include <hip/hip_runtime.h>
#include <math.h>

#define T_TOTAL 16384   // B*S
#define C_DIM   4096
#define E_DIM   64
#define K_TOP   8
#define S_SEQ   4096
#define B_BATCH 4

typedef short  short8 __attribute__((ext_vector_type(8)));
typedef float  f32x4  __attribute__((ext_vector_type(4)));

__device__ __forceinline__ unsigned short bf16_rte(float x) {
    unsigned u = __float_as_uint(x);
    return (unsigned short)((u + 0x7fffu + ((u >> 16) & 1u)) >> 16);
}
__device__ __forceinline__ float bf16_back(unsigned short h) {
    return __uint_as_float(((unsigned)h) << 16);
}

// ---- pack W into B-fragment layout, 3 bf16 split planes (r13 verbatim) ----
// wb[((s*128 + kt)*4 + n)*64 + l] = uint4 of 8 bf16:
//   elem i = split_s( W[n*16 + (l&15)][kt*32 + (l>>4)*8 + i] )
__global__ void pack_w_kernel(const float* __restrict__ w,
                              uint4* __restrict__ wb) {
    int gidx = blockIdx.x * 256 + threadIdx.x;   // [0, 98304)
    int l  = gidx & 63;
    int n  = (gidx >> 6) & 3;
    int kt = (gidx >> 8) & 127;
    int s  = gidx >> 15;                         // 0..2
    int e  = n * 16 + (l & 15);
    int kb = kt * 32 + (l >> 4) * 8;
    const float* src = w + (size_t)e * C_DIM + kb;
    unsigned short h[8];
#pragma unroll
    for (int i = 0; i < 8; ++i) {
        float v = src[i];
        unsigned short b1 = bf16_rte(v);
        if (s == 0) { h[i] = b1; continue; }
        float r = v - bf16_back(b1);             // exact (Sterbenz)
        unsigned short b2 = bf16_rte(r);
        if (s == 1) { h[i] = b2; continue; }
        float r2 = r - bf16_back(b2);            // exact
        h[i] = bf16_rte(r2);
    }
    uint4 o;
    o.x = (unsigned)h[0] | ((unsigned)h[1] << 16);
    o.y = (unsigned)h[2] | ((unsigned)h[3] << 16);
    o.z = (unsigned)h[4] | ((unsigned)h[5] << 16);
    o.w = (unsigned)h[6] | ((unsigned)h[7] << 16);
    wb[gidx] = o;
}

__device__ __forceinline__ void split3(const float xv[8],
                                       short8& A1, short8& A2, short8& A3) {
#pragma unroll
    for (int i = 0; i < 8; ++i) {
        float v = xv[i];
        unsigned short h1 = bf16_rte(v);
        float r = v - bf16_back(h1);
        unsigned short h2 = bf16_rte(r);
        float r2 = r - bf16_back(h2);
        unsigned short h3 = bf16_rte(r2);
        A1[i] = (short)h1; A2[i] = (short)h2; A3[i] = (short)h3;
    }
}

#define MFB(af, bf, acc) \
    acc = __builtin_amdgcn_mfma_f32_16x16x32_bf16(af, bf, acc, 0, 0, 0)

#define SPLIT_TILE(m, P0, P1)                                            \
    {                                                                    \
        float xv_[8] = {P0.x, P0.y, P0.z, P0.w, P1.x, P1.y, P1.z, P1.w};\
        split3(xv_, a1[m], a2[m], a3[m]);                                \
    }

// one M=64 kstep on register set (XA0..XD1); reloads that set for kstep T+2.
#define KSTEP_BODY(T, XA0, XA1, XB0, XB1, XC0, XC1, XD0, XD1)            \
    {                                                                    \
        const uint4* wstep = wbl + (size_t)(T) * 256;                    \
        uint4 q0[4], q1[4], q2[4];                                       \
        _Pragma("unroll")                                                \
        for (int n = 0; n < 4; ++n) {                                    \
            q0[n] = wstep[n * 64];                                       \
            q1[n] = wstep[32768 + n * 64];                               \
            q2[n] = wstep[65536 + n * 64];                               \
        }                                                                \
        short8 a1[4], a2[4], a3[4];                                      \
        SPLIT_TILE(0, XA0, XA1)                                          \
        SPLIT_TILE(1, XB0, XB1)                                          \
        SPLIT_TILE(2, XC0, XC1)                                          \
        SPLIT_TILE(3, XD0, XD1)                                          \
        if ((T) + 2 < 16) {                                              \
            const int o_ = ((T) + 2) * 32;                               \
            XA0 = *(const float4*)(xp0 + o_);                            \
            XA1 = *(const float4*)(xp0 + o_ + 4);                        \
            XB0 = *(const float4*)(xp1 + o_);                            \
            XB1 = *(const float4*)(xp1 + o_ + 4);                        \
            XC0 = *(const float4*)(xp2 + o_);                            \
            XC1 = *(const float4*)(xp2 + o_ + 4);                        \
            XD0 = *(const float4*)(xp3 + o_);                            \
            XD1 = *(const float4*)(xp3 + o_ + 4);                        \
        }                                                                \
        union { uint4 u; short8 v; } cv;                                 \
        _Pragma("unroll")                                                \
        for (int n = 0; n < 4; ++n) {                                    \
            cv.u = q0[n]; const short8 B1 = cv.v;                        \
            cv.u = q1[n]; const short8 B2 = cv.v;                        \
            cv.u = q2[n]; const short8 B3 = cv.v;                        \
            _Pragma("unroll")                                            \
            for (int m = 0; m < 4; ++m) {                                \
                f32x4 c = acc[m][n];                                     \
                MFB(a1[m], B1, c);                                       \
                MFB(a1[m], B2, c);                                       \
                MFB(a2[m], B1, c);                                       \
                MFB(a1[m], B3, c);                                       \
                MFB(a3[m], B1, c);                                       \
                MFB(a2[m], B2, c);                                       \
                acc[m][n] = c;                                           \
            }                                                            \
        }                                                                \
    }

// ---- fused gate: bf16x3 MFMA GEMM, M=64/wave + 2-deep x prefetch ----
// 256 blocks x 512 threads (8 waves) = 1 block/CU. Block = 64 tokens;
// wave kq (0..7): 512-ch K-eighth, M = 64 as four 16-row tiles sharing
// the same 12 B-frags. r25 change vs r24: __launch_bounds__(512,1) ->
// 256-VGPR cap (r24's (512,2) pinned VGPR to 128 and spilled 71 MB).
// Grid is already 1 block/CU so this costs zero occupancy (occupancy is
// triple-proven null). Arithmetic order bit-identical to r23/r24
// (absmax=0). Two-stage slog reduction + verified butterfly epilogue.
__global__ __launch_bounds__(512, 1)
void gate_mfma_kernel(const float* __restrict__ x,
                      const uint4* __restrict__ wb,
                      const float* __restrict__ expert_bias,
                      float* __restrict__ out,
                      float* __restrict__ facc,
                      float* __restrict__ pacc) {
    const int tid  = threadIdx.x;
    const int lane = tid & 63;
    const int kq   = tid >> 6;        // 0..7: K-eighth
    const int tok0 = blockIdx.x * 64;
    const int row  = lane & 15;
    const int g    = lane >> 4;

    __shared__ float slog[4][64][64]; // 64 KB

    const float* xp0 = x + (size_t)(tok0 + row) * C_DIM + kq * 512 + g * 8;
    const float* xp1 = xp0 + 16 * C_DIM;
    const float* xp2 = xp0 + 32 * C_DIM;
    const float* xp3 = xp0 + 48 * C_DIM;
    const uint4* wbl = wb + lane + (size_t)(kq * 16) * 256;  // + t*256

    f32x4 acc[4][4];                  // [tile][n]
#pragma unroll
    for (int m = 0; m < 4; ++m)
#pragma unroll
        for (int n = 0; n < 4; ++n)
#pragma unroll
            for (int j = 0; j < 4; ++j) acc[m][n][j] = 0.0f;

    // 2-deep x prefetch: even set (t=0) and odd set (t=1)
    float4 eA0 = *(const float4*)(xp0);
    float4 eA1 = *(const float4*)(xp0 + 4);
    float4 eB0 = *(const float4*)(xp1);
    float4 eB1 = *(const float4*)(xp1 + 4);
    float4 eC0 = *(const float4*)(xp2);
    float4 eC1 = *(const float4*)(xp2 + 4);
    float4 eD0 = *(const float4*)(xp3);
    float4 eD1 = *(const float4*)(xp3 + 4);
    float4 oA0 = *(const float4*)(xp0 + 32);
    float4 oA1 = *(const float4*)(xp0 + 36);
    float4 oB0 = *(const float4*)(xp1 + 32);
    float4 oB1 = *(const float4*)(xp1 + 36);
    float4 oC0 = *(const float4*)(xp2 + 32);
    float4 oC1 = *(const float4*)(xp2 + 36);
    float4 oD0 = *(const float4*)(xp3 + 32);
    float4 oD1 = *(const float4*)(xp3 + 36);

#pragma unroll 1
    for (int t = 0; t < 16; t += 2) {
        KSTEP_BODY(t,     eA0, eA1, eB0, eB1, eC0, eC1, eD0, eD1)
        KSTEP_BODY(t + 1, oA0, oA1, oB0, oB1, oC0, oC1, oD0, oD1)
    }

    // ---- two-stage slog reduction (race-free via barriers) ----
    if (kq < 4) {
#pragma unroll
        for (int m = 0; m < 4; ++m)
#pragma unroll
            for (int n = 0; n < 4; ++n)
#pragma unroll
                for (int r = 0; r < 4; ++r)
                    slog[kq][m * 16 + g * 4 + r][n * 16 + row] = acc[m][n][r];
    }
    __syncthreads();
    if (kq >= 4) {
        const int p = kq - 4;
#pragma unroll
        for (int m = 0; m < 4; ++m)
#pragma unroll
            for (int n = 0; n < 4; ++n)
#pragma unroll
                for (int r = 0; r < 4; ++r)
                    slog[p][m * 16 + g * 4 + r][n * 16 + row] += acc[m][n][r];
    }
    __syncthreads();

    // ---- phase 2: verified top-8 butterfly; wave kq handles 8 tokens ----
    const float be = expert_bias[lane];
    const int   b  = tok0 / S_SEQ;               // uniform per block
    float f_local = 0.0f, p_local = 0.0f;

    for (int m = 0; m < 8; ++m) {
        const int tl = kq * 8 + m;
        const int tk = tok0 + tl;
        const float logit = slog[0][tl][lane] + slog[1][tl][lane]
                          + slog[2][tl][lane] + slog[3][tl][lane];
        const float sc = 1.0f / (1.0f + expf(-logit));   // sigmoid
        float ssum = sc;
#pragma unroll
        for (int off = 32; off >= 1; off >>= 1) ssum += __shfl_xor(ssum, off, 64);
        p_local += sc / (ssum + 1e-10f);

        float v = logit + be;
        float wsum = 0.0f, my_w = 0.0f;
        int   my_i = 0;
#pragma unroll
        for (int k = 0; k < K_TOP; ++k) {
            float rv = v;
            int   ri = lane;
#pragma unroll
            for (int off = 32; off >= 1; off >>= 1) {
                float ov = __shfl_xor(rv, off, 64);
                int   oi = __shfl_xor(ri, off, 64);
                if (ov > rv || (ov == rv && oi < ri)) { rv = ov; ri = oi; }
            }
            float wsc = __shfl(sc, ri, 64);      // winner's score (uniform)
            wsum += wsc;
            if (lane == k)  { my_i = ri; my_w = wsc; }
            if (lane == ri) { v = -INFINITY; f_local += 1.0f; }
        }
        if (lane < K_TOP) {
            out[(size_t)tk * K_TOP + lane] = (float)my_i;
            out[(size_t)T_TOTAL * K_TOP + (size_t)tk * K_TOP + lane] =
                my_w / (wsum + 1e-10f);
        }
    }

    atomicAdd(&facc[b * E_DIM + lane], f_local);
    atomicAdd(&pacc[b * E_DIM + lane], p_local);
}

// ---- tiny loss reduction: 4x64 f*p -> scalar ----
__global__ void loss_kernel(const float* __restrict__ facc,
                            const float* __restrict__ pacc,
                            float* __restrict__ out_loss) {
    const int tid = threadIdx.x;                 // 256 threads = B*E
    float f = facc[tid] * (1.0f / ((float)K_TOP * (float)S_SEQ));
    float p = pacc[tid] * (1.0f / (float)S_SEQ);
    float v = f * p;
#pragma unroll
    for (int off = 32; off >= 1; off >>= 1) v += __shfl_xor(v, off, 64);
    __shared__ float sred[4];
    if ((tid & 63) == 0) sred[tid >> 6] = v;
    __syncthreads();
    if (tid == 0) {
        float tot = sred[0] + sred[1] + sred[2] + sred[3];
        out_loss[0] = 0.001f * tot / (float)B_BATCH;
    }
}

extern "C" void kernel_launch(void* const* d_in, const int* in_sizes, int n_in,
                              void* d_out, int out_size, void* d_ws, size_t ws_size,
                              hipStream_t stream) {
    const float* x    = (const float*)d_in[0];   // [4,4096,4096] f32
    const float* w    = (const float*)d_in[1];   // [64,4096] f32
    const float* bias = (const float*)d_in[2];   // [64] f32
    float* out = (float*)d_out;                  // [131072 idx][131072 w][1 loss]

    float* facc = (float*)d_ws;                  // 256 floats
    float* pacc = facc + B_BATCH * E_DIM;        // 256 floats
    uint4* wb   = (uint4*)((char*)d_ws + 4096);  // 1.5 MB packed split-W

    // zero the f/p accumulators every call (atomics accumulate)
    hipMemsetAsync(d_ws, 0, 2048, stream);

    pack_w_kernel<<<384, 256, 0, stream>>>(w, wb);

    gate_mfma_kernel<<<256, 512, 0, stream>>>(x, wb, bias, out, facc, pacc);

    loss_kernel<<<1, 256, 0, stream>>>(facc, pacc, out + 2 * (size_t)T_TOTAL * K_TOP);
}

// Round 26
// 110.388 us; speedup vs baseline: 1.3039x; 1.3039x over previous
//
#include <hip/hip_runtime.h>
#include <math.h>

#define T_TOTAL 16384   // B*S
#define C_DIM   4096
#define E_DIM   64
#define K_TOP   8
#define S_SEQ   4096
#define B_BATCH 4

typedef short  short8 __attribute__((ext_vector_type(8)));
typedef float  f32x4  __attribute__((ext_vector_type(4)));

__device__ __forceinline__ unsigned short bf16_rte(float x) {
    unsigned u = __float_as_uint(x);
    return (unsigned short)((u + 0x7fffu + ((u >> 16) & 1u)) >> 16);
}
__device__ __forceinline__ float bf16_back(unsigned short h) {
    return __uint_as_float(((unsigned)h) << 16);
}

// HW packed f32->bf16 convert: lo -> bits[15:0], hi -> bits[31:16]
__device__ __forceinline__ unsigned cvt_pk_bf16(float lo, float hi) {
    unsigned r;
    asm("v_cvt_pk_bf16_f32 %0, %1, %2" : "=v"(r) : "v"(lo), "v"(hi));
    return r;
}

// ---- pack W into B-fragment layout, 3 bf16 split planes (r13 verbatim) ----
// wb[((s*128 + kt)*4 + n)*64 + l] = uint4 of 8 bf16:
//   elem i = split_s( W[n*16 + (l&15)][kt*32 + (l>>4)*8 + i] )
__global__ void pack_w_kernel(const float* __restrict__ w,
                              uint4* __restrict__ wb) {
    int gidx = blockIdx.x * 256 + threadIdx.x;   // [0, 98304)
    int l  = gidx & 63;
    int n  = (gidx >> 6) & 3;
    int kt = (gidx >> 8) & 127;
    int s  = gidx >> 15;                         // 0..2
    int e  = n * 16 + (l & 15);
    int kb = kt * 32 + (l >> 4) * 8;
    const float* src = w + (size_t)e * C_DIM + kb;
    unsigned short h[8];
#pragma unroll
    for (int i = 0; i < 8; ++i) {
        float v = src[i];
        unsigned short b1 = bf16_rte(v);
        if (s == 0) { h[i] = b1; continue; }
        float r = v - bf16_back(b1);             // exact (Sterbenz)
        unsigned short b2 = bf16_rte(r);
        if (s == 1) { h[i] = b2; continue; }
        float r2 = r - bf16_back(b2);            // exact
        h[i] = bf16_rte(r2);
    }
    uint4 o;
    o.x = (unsigned)h[0] | ((unsigned)h[1] << 16);
    o.y = (unsigned)h[2] | ((unsigned)h[3] << 16);
    o.z = (unsigned)h[4] | ((unsigned)h[5] << 16);
    o.w = (unsigned)h[6] | ((unsigned)h[7] << 16);
    wb[gidx] = o;
}

// r26 split3: v_cvt_pk_bf16_f32-based (2.8x fewer VALU ops than manual
// integer rounding). Residuals r = v - back(b) remain exact; dropped-term
// error class unchanged (<= ~4e-6 sigma per logit).
__device__ __forceinline__ void split3(const float xv[8],
                                       short8& A1, short8& A2, short8& A3) {
    union { unsigned u[4]; short8 s; } U1, U2, U3;
#pragma unroll
    for (int p = 0; p < 4; ++p) {
        const float lo = xv[2 * p], hi = xv[2 * p + 1];
        const unsigned c1 = cvt_pk_bf16(lo, hi);
        U1.u[p] = c1;
        const float r1lo = lo - __uint_as_float(c1 << 16);
        const float r1hi = hi - __uint_as_float(c1 & 0xffff0000u);
        const unsigned c2 = cvt_pk_bf16(r1lo, r1hi);
        U2.u[p] = c2;
        const float r2lo = r1lo - __uint_as_float(c2 << 16);
        const float r2hi = r1hi - __uint_as_float(c2 & 0xffff0000u);
        U3.u[p] = cvt_pk_bf16(r2lo, r2hi);
    }
    A1 = U1.s; A2 = U2.s; A3 = U3.s;
}

#define MFB(af, bf, acc) \
    acc = __builtin_amdgcn_mfma_f32_16x16x32_bf16(af, bf, acc, 0, 0, 0)

#define SPLIT_TILE(m, P0, P1)                                            \
    {                                                                    \
        float xv_[8] = {P0.x, P0.y, P0.z, P0.w, P1.x, P1.y, P1.z, P1.w};\
        split3(xv_, a1[m], a2[m], a3[m]);                                \
    }

// ---- fused gate: bf16x3 MFMA GEMM, M=64/wave (r23 structure verbatim) ----
// 256 blocks x 512 threads (8 waves) = 1 block/CU. Block = 64 tokens;
// wave kq (0..7): 512-ch K-eighth, M = 64 as four 16-row tiles sharing
// the same 12 B-frags. 1-deep x prefetch (r23's proven register fit under
// the hard 128-VGPR cap for 512-thread blocks; r24/r25's 2-deep spilled).
// r26 change: cvt_pk-based split3 only. Everything else byte-identical to
// the r23 absmax=0 kernel. Two-stage slog reduction + verified butterfly.
__global__ __launch_bounds__(512, 2)
void gate_mfma_kernel(const float* __restrict__ x,
                      const uint4* __restrict__ wb,
                      const float* __restrict__ expert_bias,
                      float* __restrict__ out,
                      float* __restrict__ facc,
                      float* __restrict__ pacc) {
    const int tid  = threadIdx.x;
    const int lane = tid & 63;
    const int kq   = tid >> 6;        // 0..7: K-eighth
    const int tok0 = blockIdx.x * 64;
    const int row  = lane & 15;
    const int g    = lane >> 4;

    __shared__ float slog[4][64][64]; // 64 KB

    const float* xp0 = x + (size_t)(tok0 + row) * C_DIM + kq * 512 + g * 8;
    const float* xp1 = xp0 + 16 * C_DIM;
    const float* xp2 = xp0 + 32 * C_DIM;
    const float* xp3 = xp0 + 48 * C_DIM;
    const uint4* wbl = wb + lane + (size_t)(kq * 16) * 256;  // + t*256

    f32x4 acc[4][4];                  // [tile][n]
#pragma unroll
    for (int m = 0; m < 4; ++m)
#pragma unroll
        for (int n = 0; n < 4; ++n)
#pragma unroll
            for (int j = 0; j < 4; ++j) acc[m][n][j] = 0.0f;

    // 1-deep x prefetch: 8 named float4 (2 per tile)
    float4 cA0 = *(const float4*)(xp0);
    float4 cA1 = *(const float4*)(xp0 + 4);
    float4 cB0 = *(const float4*)(xp1);
    float4 cB1 = *(const float4*)(xp1 + 4);
    float4 cC0 = *(const float4*)(xp2);
    float4 cC1 = *(const float4*)(xp2 + 4);
    float4 cD0 = *(const float4*)(xp3);
    float4 cD1 = *(const float4*)(xp3 + 4);

#pragma unroll 1
    for (int t = 0; t < 16; ++t) {
        // (1) issue the 12 shared W loads
        const uint4* wstep = wbl + (size_t)t * 256;
        uint4 q0[4], q1[4], q2[4];
#pragma unroll
        for (int n = 0; n < 4; ++n) {
            q0[n] = wstep[n * 64];
            q1[n] = wstep[32768 + n * 64];
            q2[n] = wstep[65536 + n * 64];
        }

        // (2) split the 4 tiles' x (covers W latency with VALU)
        short8 a1[4], a2[4], a3[4];
        SPLIT_TILE(0, cA0, cA1)
        SPLIT_TILE(1, cB0, cB1)
        SPLIT_TILE(2, cC0, cC1)
        SPLIT_TILE(3, cD0, cD1)

        // (3) reload prefetch regs for t+1 (in flight across the MFMAs)
        if (t + 1 < 16) {
            const int o = (t + 1) * 32;
            cA0 = *(const float4*)(xp0 + o); cA1 = *(const float4*)(xp0 + o + 4);
            cB0 = *(const float4*)(xp1 + o); cB1 = *(const float4*)(xp1 + o + 4);
            cC0 = *(const float4*)(xp2 + o); cC1 = *(const float4*)(xp2 + o + 4);
            cD0 = *(const float4*)(xp3 + o); cD1 = *(const float4*)(xp3 + o + 4);
        }

        // (4) 48 MFMAs: per accumulator the canonical 6-product order
        union { uint4 u; short8 v; } cv;
#pragma unroll
        for (int n = 0; n < 4; ++n) {
            cv.u = q0[n]; const short8 B1 = cv.v;
            cv.u = q1[n]; const short8 B2 = cv.v;
            cv.u = q2[n]; const short8 B3 = cv.v;
#pragma unroll
            for (int m = 0; m < 4; ++m) {
                f32x4 c = acc[m][n];
                MFB(a1[m], B1, c);
                MFB(a1[m], B2, c);
                MFB(a2[m], B1, c);
                MFB(a1[m], B3, c);
                MFB(a3[m], B1, c);
                MFB(a2[m], B2, c);
                acc[m][n] = c;
            }
        }
    }

    // ---- two-stage slog reduction (race-free via barriers) ----
    if (kq < 4) {
#pragma unroll
        for (int m = 0; m < 4; ++m)
#pragma unroll
            for (int n = 0; n < 4; ++n)
#pragma unroll
                for (int r = 0; r < 4; ++r)
                    slog[kq][m * 16 + g * 4 + r][n * 16 + row] = acc[m][n][r];
    }
    __syncthreads();
    if (kq >= 4) {
        const int p = kq - 4;
#pragma unroll
        for (int m = 0; m < 4; ++m)
#pragma unroll
            for (int n = 0; n < 4; ++n)
#pragma unroll
                for (int r = 0; r < 4; ++r)
                    slog[p][m * 16 + g * 4 + r][n * 16 + row] += acc[m][n][r];
    }
    __syncthreads();

    // ---- phase 2: verified top-8 butterfly; wave kq handles 8 tokens ----
    const float be = expert_bias[lane];
    const int   b  = tok0 / S_SEQ;               // uniform per block
    float f_local = 0.0f, p_local = 0.0f;

    for (int m = 0; m < 8; ++m) {
        const int tl = kq * 8 + m;
        const int tk = tok0 + tl;
        const float logit = slog[0][tl][lane] + slog[1][tl][lane]
                          + slog[2][tl][lane] + slog[3][tl][lane];
        const float sc = 1.0f / (1.0f + expf(-logit));   // sigmoid
        float ssum = sc;
#pragma unroll
        for (int off = 32; off >= 1; off >>= 1) ssum += __shfl_xor(ssum, off, 64);
        p_local += sc / (ssum + 1e-10f);

        float v = logit + be;
        float wsum = 0.0f, my_w = 0.0f;
        int   my_i = 0;
#pragma unroll
        for (int k = 0; k < K_TOP; ++k) {
            float rv = v;
            int   ri = lane;
#pragma unroll
            for (int off = 32; off >= 1; off >>= 1) {
                float ov = __shfl_xor(rv, off, 64);
                int   oi = __shfl_xor(ri, off, 64);
                if (ov > rv || (ov == rv && oi < ri)) { rv = ov; ri = oi; }
            }
            float wsc = __shfl(sc, ri, 64);      // winner's score (uniform)
            wsum += wsc;
            if (lane == k)  { my_i = ri; my_w = wsc; }
            if (lane == ri) { v = -INFINITY; f_local += 1.0f; }
        }
        if (lane < K_TOP) {
            out[(size_t)tk * K_TOP + lane] = (float)my_i;
            out[(size_t)T_TOTAL * K_TOP + (size_t)tk * K_TOP + lane] =
                my_w / (wsum + 1e-10f);
        }
    }

    atomicAdd(&facc[b * E_DIM + lane], f_local);
    atomicAdd(&pacc[b * E_DIM + lane], p_local);
}

// ---- tiny loss reduction: 4x64 f*p -> scalar ----
__global__ void loss_kernel(const float* __restrict__ facc,
                            const float* __restrict__ pacc,
                            float* __restrict__ out_loss) {
    const int tid = threadIdx.x;                 // 256 threads = B*E
    float f = facc[tid] * (1.0f / ((float)K_TOP * (float)S_SEQ));
    float p = pacc[tid] * (1.0f / (float)S_SEQ);
    float v = f * p;
#pragma unroll
    for (int off = 32; off >= 1; off >>= 1) v += __shfl_xor(v, off, 64);
    __shared__ float sred[4];
    if ((tid & 63) == 0) sred[tid >> 6] = v;
    __syncthreads();
    if (tid == 0) {
        float tot = sred[0] + sred[1] + sred[2] + sred[3];
        out_loss[0] = 0.001f * tot / (float)B_BATCH;
    }
}

extern "C" void kernel_launch(void* const* d_in, const int* in_sizes, int n_in,
                              void* d_out, int out_size, void* d_ws, size_t ws_size,
                              hipStream_t stream) {
    const float* x    = (const float*)d_in[0];   // [4,4096,4096] f32
    const float* w    = (const float*)d_in[1];   // [64,4096] f32
    const float* bias = (const float*)d_in[2];   // [64] f32
    float* out = (float*)d_out;                  // [131072 idx][131072 w][1 loss]

    float* facc = (float*)d_ws;                  // 256 floats
    float* pacc = facc + B_BATCH * E_DIM;        // 256 floats
    uint4* wb   = (uint4*)((char*)d_ws + 4096);  // 1.5 MB packed split-W

    // zero the f/p accumulators every call (atomics accumulate)
    hipMemsetAsync(d_ws, 0, 2048, stream);

    pack_w_kernel<<<384, 256, 0, stream>>>(w, wb);

    gate_mfma_kernel<<<256, 512, 0, stream>>>(x, wb, bias, out, facc, pacc);

    loss_kernel<<<1, 256, 0, stream>>>(facc, pacc, out + 2 * (size_t)T_TOTAL * K_TOP);
}